// Round 5
// baseline (1612.019 us; speedup 1.0000x reference)
//
#include <hip/hip_runtime.h>
#include <hip/hip_bf16.h>
#include <math.h>

typedef __hip_bfloat16 bf16;

#define NNODES 358
#define NN2 (358*358)
#define DIM 96
#define PP 72
#define ND 64
#define NB 8
#define NH 4
#define SEQ (NB*NNODES)

// ---- workspace layout (float offsets). total 3,328,112 floats = 13.3 MB ----
#define WS_WT2   0            // 4*96*72: per-head transposed in_proj (f32)
#define WS_WBAR  27648        // 96
#define WS_BBAR  27744        // 1 (pad to 27752)
#define WS_PRM   27752        // SEQ*96
#define WS_DEA   302696       // SEQ*64
#define WS_DEB   485992       // SEQ*64
#define WS_DETG  669288       // 8*64*360
#define WS_FLAG  853608       // 1 : input dtype flag (1.0=f32, 0.0=bf16), pad to 853616
#define WS_AO    853616       // 358*72*96 : attention out, 1-batch ring

__device__ __forceinline__ float ldv(const float* p, size_t i) { return p[i]; }
__device__ __forceinline__ float ldv(const bf16* p, size_t i)  { return __bfloat162float(p[i]); }
__device__ __forceinline__ float gelu_f(float y) {
  return 0.5f*y*(1.0f+erff(y*0.70710678118654752440f));
}

template<typename T> struct IsF32 { static constexpr bool v = false; };
template<> struct IsF32<float>   { static constexpr bool v = true;  };
#define MODE_GUARD(W) do { if ((((const float*)(W))[WS_FLAG] != 0.0f) != IsF32<T>::v) return; } while (0)

// ------------------------------------------------ kD: input dtype detector
// f32 storage read as u16: low halves are mantissa garbage -> ~46% of 8192
// samples have "bf16 exponent" >= 137. True bf16 N(0,1) storage: ~0.
__global__ void kD_detect(const unsigned short* __restrict__ raw, float* __restrict__ ws)
{
  __shared__ int cnt;
  if (threadIdx.x == 0) cnt = 0;
  __syncthreads();
  int loc = 0;
  for (int i = threadIdx.x; i < 8192; i += 256) {
    int ex = (raw[i] >> 7) & 0xFF;
    if (ex >= 137) ++loc;
  }
  atomicAdd(&cnt, loc);
  __syncthreads();
  if (threadIdx.x == 0) ws[WS_FLAG] = (cnt > 64) ? 1.0f : 0.0f;
}

// ---------------------------------------------------------------- k0: setup
template<typename T>
__global__ void k0_setup(const T* __restrict__ wi, const T* __restrict__ wo,
                         const T* __restrict__ bo, float* __restrict__ ws)
{
  MODE_GUARD(ws);
  int t = threadIdx.x;
  for (int idx = t; idx < 4*96*72; idx += 256) {
    int h = idx / (96*72);
    int r = idx - h*96*72;
    int k = r / 72;
    int gc = r - k*72;
    int g = gc / 24, c = gc - g*24;
    ws[WS_WT2 + idx] = ldv(wi, (size_t)(g*96 + h*24 + c)*96 + k);
  }
  if (t < 96) {
    float sm = 0.0f;
    for (int d = 0; d < 96; ++d) sm += ldv(wo, d*96 + t);
    ws[WS_WBAR + t] = sm*(1.0f/96.0f);
  }
  if (t == 0) {
    float sm = 0.0f;
    for (int d = 0; d < 96; ++d) sm += ldv(bo, d);
    ws[WS_BBAR] = sm*(1.0f/96.0f);
  }
}

// ------------------------------------------- shared softmax + top-10 helper
// lg[358] logits (destroyed), pb[358] scratch; selection on logits, tie->lower idx
__device__ void softmax_topk_row(float* lg, float* pb, float* redv, int* redi,
                                 float* sc, int* sel, float* outrow)
{
  int t = threadIdx.x;
  int lane = t & 63, w = t >> 6;
  float mx = -1e30f;
  for (int m = t; m < NNODES; m += 256) mx = fmaxf(mx, lg[m]);
  for (int o = 32; o; o >>= 1) mx = fmaxf(mx, __shfl_down(mx, o, 64));
  if (lane == 0) redv[w] = mx;
  __syncthreads();
  if (t == 0) sc[0] = fmaxf(fmaxf(redv[0], redv[1]), fmaxf(redv[2], redv[3]));
  __syncthreads();
  float M = sc[0];
  float ls = 0.0f;
  for (int m = t; m < NNODES; m += 256) { float e = __expf(lg[m]-M); pb[m] = e; ls += e; }
  for (int o = 32; o; o >>= 1) ls += __shfl_down(ls, o, 64);
  if (lane == 0) redv[w] = ls;
  __syncthreads();
  if (t == 0) sc[1] = redv[0]+redv[1]+redv[2]+redv[3];
  __syncthreads();
  float invS = 1.0f/sc[1];
  for (int it = 0; it < 10; ++it) {
    float v = -1e30f; int idx = 0x7fffffff;
    for (int m = t; m < NNODES; m += 256) {
      float x = lg[m];
      if (x > v) { v = x; idx = m; }
    }
    for (int o = 32; o; o >>= 1) {
      float ov = __shfl_down(v, o, 64);
      int oi = __shfl_down(idx, o, 64);
      if (ov > v || (ov == v && oi < idx)) { v = ov; idx = oi; }
    }
    if (lane == 0) { redv[w] = v; redi[w] = idx; }
    __syncthreads();
    if (t == 0) {
      float bv = redv[0]; int bidx = redi[0];
      for (int k = 1; k < 4; ++k)
        if (redv[k] > bv || (redv[k] == bv && redi[k] < bidx)) { bv = redv[k]; bidx = redi[k]; }
      sel[it] = bidx;
      lg[bidx] = -1e30f;
    }
    __syncthreads();
  }
  if (t == 0) {
    float ss = 0.0f;
    for (int k = 0; k < 10; ++k) ss += pb[sel[k]]*invS;
    sc[0] = ss + 1e-8f;
  }
  __syncthreads();
  float dn = 1.0f/sc[0];
  for (int m = t; m < NNODES; m += 256) {
    float val = 0.0f;
    #pragma unroll
    for (int k = 0; k < 10; ++k) val = (m == sel[k]) ? pb[m]*invS*dn : val;
    outrow[m] = val;
  }
}

// --------------------------------------------------- k1: static adjacencies
template<typename T>
__global__ void __launch_bounds__(256)
k1_static(const T* __restrict__ le1, const T* __restrict__ le2,
          const T* __restrict__ ge1, const T* __restrict__ ge2,
          const T* __restrict__ temp, const float* __restrict__ ws,
          float* __restrict__ outstat)
{
  MODE_GUARD(ws);
  __shared__ float e1[64], lg[NNODES], pb[NNODES], redv[4], sc[2];
  __shared__ int redi[4], sel[10];
  int blk = blockIdx.x, t = threadIdx.x;
  int h = blk / NNODES, n = blk - h*NNODES;
  int kd; const T *e1p, *e2p; float tau;
  if (h < 2) {
    kd = 32;
    e1p = le1 + ((size_t)h*NNODES + n)*32;
    e2p = le2 + (size_t)h*32*NNODES;
    tau = fminf(fmaxf(ldv(temp, h)*2.0f, 0.1f), 5.0f);
  } else {
    kd = 64;
    e1p = ge1 + ((size_t)(h-2)*NNODES + n)*64;
    e2p = ge2 + (size_t)(h-2)*64*NNODES;
    tau = fminf(fmaxf(ldv(temp, h)*0.5f, 0.1f), 2.0f);
  }
  if (t < kd) e1[t] = ldv(e1p, t);
  __syncthreads();
  for (int m = t; m < NNODES; m += 256) {
    float s = 0.0f;
    for (int k = 0; k < kd; ++k) s += e1[k]*ldv(e2p, k*NNODES + m);
    lg[m] = fmaxf(s, 0.0f)/tau;
  }
  __syncthreads();
  softmax_topk_row(lg, pb, redv, redi, sc, sel, outstat + (size_t)blk*NNODES);
}

// --------------------------------------- k2a: per-(seq,head) attention
// LDS 12960 floats = 51,840 B (launch-safe)
#define A_XS  0        // 72x100 x tile; S (72x76) aliases this after QKV
#define A_QH  7200
#define A_KT  9216
#define A_VT  11040
#define A_TOT 12960

template<typename T>
__global__ void __launch_bounds__(256)
k2a_attn(const T* __restrict__ pf, const T* __restrict__ pos,
         const T* __restrict__ inb, float* __restrict__ ws, int B0)
{
  MODE_GUARD(ws);
  __shared__ float L[A_TOT];
  int blk = blockIdx.x, t = threadIdx.x;
  int h = blk & 3;
  int n = blk >> 2;
  size_t s = (size_t)B0*NNODES + n;
  const T* prp = pf + s*(PP*DIM);
  for (int idx = t; idx < PP*DIM; idx += 256) {
    int p = idx/DIM, e = idx - p*DIM;
    L[A_XS + p*100 + e] = ldv(prp, idx);
  }
  __syncthreads();
  if (h == 0 && t < DIM) {            // pf.mean over P (pre pos-enc)
    float sm = 0.0f;
    for (int p = 0; p < PP; ++p) sm += L[A_XS + p*100 + t];
    ws[WS_PRM + s*DIM + t] = sm*(1.0f/72.0f);
  }
  __syncthreads();
  for (int idx = t; idx < PP*DIM; idx += 256) {
    int p = idx/DIM, e = idx - p*DIM;
    L[A_XS + p*100 + e] += ldv(pos, idx);
  }
  __syncthreads();
  const float* Wt2 = ws + WS_WT2 + (size_t)h*96*72;
  const float SC = 0.20412414523193150f;  // 1/sqrt(24)
  if (t < 216) {                      // QKV: 18 p-tiles(4) x 12 col-tiles(6)
    int pt = t / 12, jt = t - pt*12;
    int p0 = pt*4, gc0 = jt*6;
    float acc[4][6];
    #pragma unroll
    for (int a = 0; a < 4; ++a)
      #pragma unroll
      for (int c = 0; c < 6; ++c) acc[a][c] = 0.0f;
    for (int k0 = 0; k0 < 96; k0 += 4) {
      float4 xv[4];
      #pragma unroll
      for (int a = 0; a < 4; ++a) xv[a] = *(const float4*)&L[A_XS + (p0+a)*100 + k0];
      const float* wr = Wt2 + (size_t)k0*72 + gc0;
      #pragma unroll
      for (int kk = 0; kk < 4; ++kk) {
        float2 w01 = *(const float2*)(wr + kk*72);
        float2 w23 = *(const float2*)(wr + kk*72 + 2);
        float2 w45 = *(const float2*)(wr + kk*72 + 4);
        float wv[6] = {w01.x, w01.y, w23.x, w23.y, w45.x, w45.y};
        #pragma unroll
        for (int a = 0; a < 4; ++a) {
          float xa = ((const float*)&xv[a])[kk];
          #pragma unroll
          for (int c = 0; c < 6; ++c) acc[a][c] += xa*wv[c];
        }
      }
    }
    int g = jt >> 2;          // 0=q,1=k,2=v
    int c0 = (jt & 3)*6;
    #pragma unroll
    for (int c = 0; c < 6; ++c) {
      int cc = c0 + c;
      float bias = ldv(inb, g*96 + h*24 + cc);
      #pragma unroll
      for (int a = 0; a < 4; ++a) {
        float v = acc[a][c] + bias;
        int p = p0 + a;
        if (g == 0)      L[A_QH + p*28 + cc] = v*SC;
        else if (g == 1) L[A_KT + cc*76 + p] = v;
        else             L[A_VT + cc*76 + p] = v;
      }
    }
  }
  __syncthreads();
  for (int tile = t; tile < 648; tile += 256) {  // S = q k^T (aliases XS, stride 76)
    int pt = tile / 18, jt = tile - pt*18;
    int p0 = pt*2, j0 = jt*4;
    float a0=0,a1=0,a2=0,a3=0, c0=0,c1=0,c2=0,c3=0;
    #pragma unroll
    for (int d0 = 0; d0 < 24; d0 += 4) {
      float4 q0 = *(const float4*)&L[A_QH + p0*28 + d0];
      float4 q1 = *(const float4*)&L[A_QH + (p0+1)*28 + d0];
      #pragma unroll
      for (int dd = 0; dd < 4; ++dd) {
        float4 kv = *(const float4*)&L[A_KT + (d0+dd)*76 + j0];
        float qa = ((const float*)&q0)[dd];
        float qb = ((const float*)&q1)[dd];
        a0 += qa*kv.x; a1 += qa*kv.y; a2 += qa*kv.z; a3 += qa*kv.w;
        c0 += qb*kv.x; c1 += qb*kv.y; c2 += qb*kv.z; c3 += qb*kv.w;
      }
    }
    *(float4*)&L[A_XS + p0*76 + j0]     = make_float4(a0,a1,a2,a3);
    *(float4*)&L[A_XS + (p0+1)*76 + j0] = make_float4(c0,c1,c2,c3);
  }
  __syncthreads();
  if (t < 72) {                       // row softmax
    float* row = &L[A_XS + t*76];
    float mx = row[0];
    for (int j = 1; j < 72; ++j) mx = fmaxf(mx, row[j]);
    float sm = 0.0f;
    for (int j = 0; j < 72; ++j) { float e = __expf(row[j]-mx); row[j] = e; sm += e; }
    float inv = 1.0f/sm;
    for (int j = 0; j < 72; ++j) row[j] *= inv;
  }
  __syncthreads();
  if (t < 216) {                      // O = P @ V -> ao ring (f32)
    int pt = t / 6, dt = t - pt*6;
    int p0 = pt*2, d0 = dt*4;
    float acc[2][4];
    #pragma unroll
    for (int a = 0; a < 2; ++a)
      #pragma unroll
      for (int dd = 0; dd < 4; ++dd) acc[a][dd] = 0.0f;
    for (int j0 = 0; j0 < 72; j0 += 4) {
      float4 pv0 = *(const float4*)&L[A_XS + p0*76 + j0];
      float4 pv1 = *(const float4*)&L[A_XS + (p0+1)*76 + j0];
      #pragma unroll
      for (int dd = 0; dd < 4; ++dd) {
        float4 vv = *(const float4*)&L[A_VT + (d0+dd)*76 + j0];
        acc[0][dd] += pv0.x*vv.x + pv0.y*vv.y + pv0.z*vv.z + pv0.w*vv.w;
        acc[1][dd] += pv1.x*vv.x + pv1.y*vv.y + pv1.z*vv.z + pv1.w*vv.w;
      }
    }
    float* aob = ws + WS_AO + (size_t)n*PP*DIM;
    #pragma unroll
    for (int a = 0; a < 2; ++a)
      #pragma unroll
      for (int dd = 0; dd < 4; ++dd)
        aob[(p0+a)*DIM + h*24 + d0 + dd] = acc[a][dd];
  }
}

// -------------------- k2b: node epilogue + dynamic encoder
#define B_AO   0      // 72 x 97
#define B_LIMP 6984
#define B_IMP  7056
#define B_WSUM 7128
#define B_NB   7224
#define B_NR   7320
#define B_WB   7416
#define B_H1   7512
#define B_G1   7640
#define B_H2   7768
#define B_TOT  7832

template<typename T>
__global__ void __launch_bounds__(128)
k2b_node(float* __restrict__ ws,
         const T* __restrict__ wo, const T* __restrict__ bo,
         const T* __restrict__ tng, const T* __restrict__ tnb,
         const T* __restrict__ dw1, const T* __restrict__ db1,
         const T* __restrict__ dg1, const T* __restrict__ dlb1,
         const T* __restrict__ dw2, const T* __restrict__ db2,
         const T* __restrict__ dg2, const T* __restrict__ dlb2, int B0)
{
  MODE_GUARD(ws);
  __shared__ float L[B_TOT];
  int n = blockIdx.x, t = threadIdx.x;
  size_t s = (size_t)B0*NNODES + n;
  const float* aob = ws + WS_AO + (size_t)n*PP*DIM;
  for (int idx = t; idx < PP*DIM; idx += 128) {
    int p = idx/DIM, e = idx - p*DIM;
    L[B_AO + p*97 + e] = aob[idx];
  }
  if (t < 96) L[B_WB + t] = ws[WS_WBAR + t];
  __syncthreads();
  if (t < 72) {    // att.mean(-1) == ao . wbar + bbar
    float sm = 0.0f;
    for (int e = 0; e < 96; ++e) sm += L[B_AO + t*97 + e]*L[B_WB + e];
    L[B_LIMP + t] = sm + ws[WS_BBAR];
  }
  __syncthreads();
  if (t < 72) {
    float mx = L[B_LIMP];
    for (int j = 1; j < 72; ++j) mx = fmaxf(mx, L[B_LIMP+j]);
    float sm = 0.0f;
    for (int j = 0; j < 72; ++j) sm += __expf(L[B_LIMP+j]-mx);
    L[B_IMP + t] = __expf(L[B_LIMP+t]-mx)/sm;
  }
  __syncthreads();
  if (t < 96) {
    float sm = 0.0f;
    for (int p = 0; p < PP; ++p) sm += L[B_IMP+p]*L[B_AO + p*97 + t];
    L[B_WSUM + t] = sm;
  }
  __syncthreads();
  if (t < 96) {
    float sm = 0.0f;
    for (int e = 0; e < 96; ++e) sm += L[B_WSUM+e]*ldv(wo, t*96 + e);
    L[B_NB + t] = sm + ldv(bo, t) + ws[WS_PRM + s*DIM + t];
  }
  __syncthreads();
  if (t < 96) {
    float mean = 0.0f;
    for (int e = 0; e < 96; ++e) mean += L[B_NB+e];
    mean *= (1.0f/96.0f);
    float var = 0.0f;
    for (int e = 0; e < 96; ++e) { float d = L[B_NB+e]-mean; var += d*d; }
    var *= (1.0f/96.0f);
    L[B_NR + t] = (L[B_NB+t]-mean)*rsqrtf(var+1e-5f)*ldv(tng, t) + ldv(tnb, t);
  }
  __syncthreads();
  {
    float sm = 0.0f;
    for (int k = 0; k < 96; ++k) sm += L[B_NR+k]*ldv(dw1, t*96 + k);
    L[B_H1 + t] = sm + ldv(db1, t);
  }
  __syncthreads();
  {
    float mean = 0.0f; for (int e = 0; e < 128; ++e) mean += L[B_H1+e];
    mean *= (1.0f/128.0f);
    float var = 0.0f; for (int e = 0; e < 128; ++e) { float d = L[B_H1+e]-mean; var += d*d; }
    var *= (1.0f/128.0f);
    float y = (L[B_H1+t]-mean)*rsqrtf(var+1e-5f)*ldv(dg1, t) + ldv(dlb1, t);
    L[B_G1 + t] = gelu_f(y);
  }
  __syncthreads();
  if (t < 64) {
    float sm = 0.0f;
    for (int k = 0; k < 128; ++k) sm += L[B_G1+k]*ldv(dw2, t*128 + k);
    L[B_H2 + t] = sm + ldv(db2, t);
  }
  __syncthreads();
  if (t < 64) {
    float mean = 0.0f; for (int e = 0; e < 64; ++e) mean += L[B_H2+e];
    mean *= (1.0f/64.0f);
    float var = 0.0f; for (int e = 0; e < 64; ++e) { float d = L[B_H2+e]-mean; var += d*d; }
    var *= (1.0f/64.0f);
    ws[WS_DEA + s*ND + t] = (L[B_H2+t]-mean)*rsqrtf(var+1e-5f)*ldv(dg2, t) + ldv(dlb2, t);
  }
}

// ------------------------------------------------ k4t: transpose de for GNN
__global__ void k4t_transpose(float* __restrict__ ws, int deoff)
{
  int bd = blockIdx.x;
  int b = bd >> 6, d = bd & 63;
  for (int m = threadIdx.x; m < NNODES; m += 256)
    ws[WS_DETG + (size_t)bd*360 + m] = ws[deoff + ((size_t)b*NNODES + m)*ND + d];
}

// --------------------------------------------------------- k4: one GNN layer
template<typename T>
__global__ void __launch_bounds__(256)
k4_gnn(float* __restrict__ ws, int inoff, int outoff,
       const T* __restrict__ w, const T* __restrict__ bb,
       const T* __restrict__ g, const T* __restrict__ beta)
{
  MODE_GUARD(ws);
  __shared__ float nrow[64], lg[NNODES], pb[NNODES], aggb[64], prj[64], redv[4], sc[2];
  int blk = blockIdx.x, t = threadIdx.x;
  int b = blk / NNODES;
  if (t < 64) nrow[t] = ws[inoff + (size_t)blk*ND + t];
  __syncthreads();
  const float* dg = ws + WS_DETG + (size_t)b*64*360;
  for (int m = t; m < NNODES; m += 256) {
    float sm = 0.0f;
    for (int d = 0; d < 64; ++d) sm += nrow[d]*dg[d*360 + m];
    lg[m] = sm/0.2f;
  }
  __syncthreads();
  int lane = t & 63, wv = t >> 6;
  float mx = -1e30f;
  for (int m = t; m < NNODES; m += 256) mx = fmaxf(mx, lg[m]);
  for (int o = 32; o; o >>= 1) mx = fmaxf(mx, __shfl_down(mx, o, 64));
  if (lane == 0) redv[wv] = mx;
  __syncthreads();
  if (t == 0) sc[0] = fmaxf(fmaxf(redv[0],redv[1]),fmaxf(redv[2],redv[3]));
  __syncthreads();
  float M = sc[0];
  float ls = 0.0f;
  for (int m = t; m < NNODES; m += 256) { float e = __expf(lg[m]-M); pb[m] = e; ls += e; }
  for (int o = 32; o; o >>= 1) ls += __shfl_down(ls, o, 64);
  if (lane == 0) redv[wv] = ls;
  __syncthreads();
  if (t == 0) sc[1] = redv[0]+redv[1]+redv[2]+redv[3];
  __syncthreads();
  float inv = 1.0f/sc[1];
  for (int m = t; m < NNODES; m += 256) pb[m] *= inv;
  __syncthreads();
  if (t < 64) {
    const float* dr = dg + (size_t)t*360;
    float sm = 0.0f;
    for (int m = 0; m < NNODES; ++m) sm += pb[m]*dr[m];
    aggb[t] = sm;
  }
  __syncthreads();
  if (t < 64) {
    float sm = 0.0f;
    for (int d = 0; d < 64; ++d) sm += aggb[d]*ldv(w, t*64 + d);
    prj[t] = sm + ldv(bb, t);
  }
  __syncthreads();
  if (t < 64) {
    float mean = 0.0f; for (int e = 0; e < 64; ++e) mean += prj[e];
    mean *= (1.0f/64.0f);
    float var = 0.0f; for (int e = 0; e < 64; ++e) { float d = prj[e]-mean; var += d*d; }
    var *= (1.0f/64.0f);
    float y = (prj[t]-mean)*rsqrtf(var+1e-5f)*ldv(g, t) + ldv(beta, t);
    ws[outoff + (size_t)blk*ND + t] = gelu_f(y) + nrow[t];
  }
}

// ----------------------------------------------- k5: dynamic adj + top-k
template<typename T>
__global__ void __launch_bounds__(256)
k5_dyn(const float* __restrict__ ws, const T* __restrict__ se2,
       const T* __restrict__ temp, float* __restrict__ outdyn)
{
  MODE_GUARD(ws);
  __shared__ float den[64], lg[NNODES], pb[NNODES], redv[4], sc[2];
  __shared__ int redi[4], sel[10];
  int blk = blockIdx.x, t = threadIdx.x;
  int n = blk % NNODES;
  int bh = blk / NNODES;
  int h = bh & 3, b = bh >> 2;
  if (t < 64) den[t] = ws[WS_DEA + ((size_t)b*NNODES + n)*ND + t];
  __syncthreads();
  float tau = fminf(fmaxf(ldv(temp, h), 0.1f), 2.0f);
  const T* sp = se2 + (size_t)h*64*NNODES;
  for (int m = t; m < NNODES; m += 256) {
    float sm = 0.0f;
    for (int d = 0; d < 64; ++d) sm += den[d]*ldv(sp, d*NNODES + m);
    lg[m] = fmaxf(sm, 0.0f)/tau;
  }
  __syncthreads();
  softmax_topk_row(lg, pb, redv, redi, sc, sel, outdyn + (size_t)blk*NNODES);
}

// ---------------------------------- k6: fusion + edge encoder + final adj
template<typename T>
__global__ void __launch_bounds__(256)
k6_fuse(const float* __restrict__ ws, const float* __restrict__ outstat,
        const float* __restrict__ outdyn,
        const T* __restrict__ gfw, const T* __restrict__ gfb,
        const T* __restrict__ ew1, const T* __restrict__ eb1,
        const T* __restrict__ elg, const T* __restrict__ elb,
        const T* __restrict__ ew2, const T* __restrict__ eb2,
        const T* __restrict__ ew3, const T* __restrict__ eb3,
        float* __restrict__ outfin)
{
  MODE_GUARD(ws);
  __shared__ float sw1[64], sb1[16], slg[16], slb[16], sw2[128], sb2[8], sw3[8], sb3[1], sfw[4];
  int blk = blockIdx.x, t = threadIdx.x;
  int b = blk / NNODES, n = blk - b*NNODES;
  if (t < 64)  sw1[t] = ldv(ew1, t);
  if (t < 16)  { sb1[t] = ldv(eb1, t); slg[t] = ldv(elg, t); slb[t] = ldv(elb, t); }
  if (t < 128) sw2[t] = ldv(ew2, t);
  if (t < 8)   { sb2[t] = ldv(eb2, t); sw3[t] = ldv(ew3, t); }
  if (t == 0)  sb3[0] = ldv(eb3, 0);
  if (t < 4) {
    const float* pm = ws + WS_PRM + (size_t)blk*DIM;
    float sm = ldv(gfb, t);
    for (int e = 0; e < DIM; ++e) sm += pm[e]*ldv(gfw, t*DIM + e);
    sfw[t] = 1.0f/(1.0f+__expf(-sm));
  }
  __syncthreads();
  size_t srow = (size_t)n*NNODES;
  for (int m = t; m < NNODES; m += 256) {
    float fu[4]; float mn = 0.0f;
    #pragma unroll
    for (int hh = 0; hh < 4; ++hh) {
      float sv = outstat[(size_t)hh*NN2 + srow + m];
      float dv = outdyn[((size_t)(b*4+hh)*NNODES + n)*NNODES + m];
      float f = (1.0f - sfw[hh])*sv + sfw[hh]*dv;
      fu[hh] = f; mn += f;
    }
    mn *= 0.25f;
    float h1[16]; float m1 = 0.0f;
    #pragma unroll
    for (int j = 0; j < 16; ++j) {
      float sm = sb1[j];
      #pragma unroll
      for (int c = 0; c < 4; ++c) sm += fu[c]*sw1[j*4+c];
      h1[j] = sm; m1 += sm;
    }
    m1 *= (1.0f/16.0f);
    float v1 = 0.0f;
    #pragma unroll
    for (int j = 0; j < 16; ++j) { float d = h1[j]-m1; v1 += d*d; }
    float is1 = rsqrtf(v1*(1.0f/16.0f) + 1e-5f);
    #pragma unroll
    for (int j = 0; j < 16; ++j) h1[j] = gelu_f((h1[j]-m1)*is1*slg[j] + slb[j]);
    float h2[8];
    #pragma unroll
    for (int i = 0; i < 8; ++i) {
      float sm = sb2[i];
      #pragma unroll
      for (int j = 0; j < 16; ++j) sm += h1[j]*sw2[i*16+j];
      h2[i] = gelu_f(sm);
    }
    float ewv = sb3[0];
    #pragma unroll
    for (int i = 0; i < 8; ++i) ewv += h2[i]*sw3[i];
    float fin = (1.0f/(1.0f+__expf(-ewv)))*mn;
    outfin[(size_t)b*NN2 + srow + m] = fin;
  }
}

// ------------------------------------------------------------- launch
template<typename T>
static void launch_all(void* const* d_in, float* ws, float* out, hipStream_t stream)
{
  const T* pf   = (const T*)d_in[0];
  const T* se2  = (const T*)d_in[1];
  const T* le1  = (const T*)d_in[2];
  const T* le2  = (const T*)d_in[3];
  const T* ge1  = (const T*)d_in[4];
  const T* ge2  = (const T*)d_in[5];
  const T* temp = (const T*)d_in[6];
  const T* wi   = (const T*)d_in[7];
  const T* inb  = (const T*)d_in[8];
  const T* wo   = (const T*)d_in[9];
  const T* bo   = (const T*)d_in[10];
  const T* tng  = (const T*)d_in[11];
  const T* tnb  = (const T*)d_in[12];
  const T* dw1  = (const T*)d_in[13];
  const T* db1  = (const T*)d_in[14];
  const T* dg1  = (const T*)d_in[15];
  const T* dlb1 = (const T*)d_in[16];
  const T* dw2  = (const T*)d_in[17];
  const T* db2  = (const T*)d_in[18];
  const T* dg2  = (const T*)d_in[19];
  const T* dlb2 = (const T*)d_in[20];
  const T* pos  = (const T*)d_in[21];
  const T* g1w  = (const T*)d_in[22];
  const T* g1b  = (const T*)d_in[23];
  const T* g1g  = (const T*)d_in[24];
  const T* g1be = (const T*)d_in[25];
  const T* g2w  = (const T*)d_in[26];
  const T* g2b  = (const T*)d_in[27];
  const T* g2g  = (const T*)d_in[28];
  const T* g2be = (const T*)d_in[29];
  const T* gfw  = (const T*)d_in[30];
  const T* gfb  = (const T*)d_in[31];
  const T* ew1  = (const T*)d_in[32];
  const T* eb1  = (const T*)d_in[33];
  const T* elg  = (const T*)d_in[34];
  const T* elb  = (const T*)d_in[35];
  const T* ew2  = (const T*)d_in[36];
  const T* eb2  = (const T*)d_in[37];
  const T* ew3  = (const T*)d_in[38];
  const T* eb3  = (const T*)d_in[39];
  float* outfin  = out;                            // (B,N,N)
  float* outstat = out + (size_t)NB*NN2;           // (H,N,N)
  float* outdyn  = out + (size_t)(NB+NH)*NN2;      // (B,H,N,N)

  k0_setup<T><<<1, 256, 0, stream>>>(wi, wo, bo, ws);
  k1_static<T><<<NH*NNODES, 256, 0, stream>>>(le1, le2, ge1, ge2, temp, ws, outstat);
  for (int B0 = 0; B0 < NB; ++B0) {
    k2a_attn<T><<<NNODES*4, 256, 0, stream>>>(pf, pos, inb, ws, B0);
    k2b_node<T><<<NNODES, 128, 0, stream>>>(ws, wo, bo, tng, tnb,
                                            dw1, db1, dg1, dlb1, dw2, db2, dg2, dlb2, B0);
  }
  k4t_transpose<<<512, 256, 0, stream>>>(ws, WS_DEA);
  k4_gnn<T><<<SEQ, 256, 0, stream>>>(ws, WS_DEA, WS_DEB, g1w, g1b, g1g, g1be);
  k4t_transpose<<<512, 256, 0, stream>>>(ws, WS_DEB);
  k4_gnn<T><<<SEQ, 256, 0, stream>>>(ws, WS_DEB, WS_DEA, g2w, g2b, g2g, g2be);
  k5_dyn<T><<<NB*NH*NNODES, 256, 0, stream>>>(ws, se2, temp, outdyn);
  k6_fuse<T><<<SEQ, 256, 0, stream>>>(ws, outstat, outdyn, gfw, gfb,
                                      ew1, eb1, elg, elb, ew2, eb2, ew3, eb3, outfin);
}

extern "C" void kernel_launch(void* const* d_in, const int* in_sizes, int n_in,
                              void* d_out, int out_size, void* d_ws, size_t ws_size,
                              hipStream_t stream)
{
  float* ws = (float*)d_ws;
  float* out = (float*)d_out;      // reference outputs are float32
  kD_detect<<<1, 256, 0, stream>>>((const unsigned short*)d_in[0], ws);
  launch_all<float>(d_in, ws, out, stream);
  launch_all<bf16>(d_in, ws, out, stream);
}

// Round 6
// 1186.416 us; speedup vs baseline: 1.3587x; 1.3587x over previous
//
#include <hip/hip_runtime.h>
#include <hip/hip_bf16.h>
#include <math.h>

#define NNODES 358
#define NN2 (358*358)
#define DIM 96
#define PP 72
#define ND 64
#define NB 8
#define NH 4
#define SEQ (NB*NNODES)

// ---- workspace layout (float offsets) ----
// base: 853,616 floats = 3.41 MB; full-batch ao adds 19,795,968 -> 82.6 MB total
#define WS_WT2   0            // 4*96*72: per-head transposed in_proj
#define WS_WBAR  27648        // 96
#define WS_BBAR  27744        // 1 (pad to 27752)
#define WS_PRM   27752        // SEQ*96
#define WS_DEA   302696       // SEQ*64
#define WS_DEB   485992       // SEQ*64
#define WS_DETG  669288       // 8*64*360
#define WS_AO    853616       // ao: ring = 358*72*96, full = SEQ*72*96

__device__ __forceinline__ float gelu_f(float y) {
  return 0.5f*y*(1.0f+erff(y*0.70710678118654752440f));
}

// ---------------------------------------------------------------- k0: setup
__global__ void k0_setup(const float* __restrict__ wi, const float* __restrict__ wo,
                         const float* __restrict__ bo, float* __restrict__ ws)
{
  int t = threadIdx.x;
  for (int idx = t; idx < 4*96*72; idx += 256) {
    int h = idx / (96*72);
    int r = idx - h*96*72;
    int k = r / 72;
    int gc = r - k*72;
    int g = gc / 24, c = gc - g*24;
    ws[WS_WT2 + idx] = wi[(size_t)(g*96 + h*24 + c)*96 + k];
  }
  if (t < 96) {
    float sm = 0.0f;
    for (int d = 0; d < 96; ++d) sm += wo[d*96 + t];
    ws[WS_WBAR + t] = sm*(1.0f/96.0f);
  }
  if (t == 0) {
    float sm = 0.0f;
    for (int d = 0; d < 96; ++d) sm += bo[d];
    ws[WS_BBAR] = sm*(1.0f/96.0f);
  }
}

// ------------------------------------------- softmax + top-10 (wave-register)
// lg[358] logits in LDS (preserved), pb[358] exp scratch.
// Selection: wave 0 only, 6 logits/lane in registers, butterfly argmax via
// shfl_xor -> zero barriers inside the 10-iteration loop (was 20). Tie -> lower idx.
__device__ void softmax_topk_row(float* lg, float* pb, float* redv,
                                 float* sc, int* sel, float* outrow)
{
  int t = threadIdx.x;
  int lane = t & 63, w = t >> 6;
  float mx = -1e30f;
  for (int m = t; m < NNODES; m += 256) mx = fmaxf(mx, lg[m]);
  for (int o = 32; o; o >>= 1) mx = fmaxf(mx, __shfl_down(mx, o, 64));
  if (lane == 0) redv[w] = mx;
  __syncthreads();
  float M = fmaxf(fmaxf(redv[0], redv[1]), fmaxf(redv[2], redv[3]));
  float ls = 0.0f;
  for (int m = t; m < NNODES; m += 256) { float e = __expf(lg[m]-M); pb[m] = e; ls += e; }
  for (int o = 32; o; o >>= 1) ls += __shfl_down(ls, o, 64);
  __syncthreads();                 // all waves done reading redv (M) before rewrite
  if (lane == 0) redv[w] = ls;
  __syncthreads();
  float invS = 1.0f/(redv[0]+redv[1]+redv[2]+redv[3]);
  if (w == 0) {                    // wave-0 register top-k, barrier-free loop
    float vals[6];
    #pragma unroll
    for (int j = 0; j < 6; ++j) {
      int m = lane + 64*j;
      vals[j] = (m < NNODES) ? lg[m] : -1e30f;
    }
    float ss = 0.0f;
    for (int it = 0; it < 10; ++it) {
      float v = -1e30f; int idx = 0x7fffffff;
      #pragma unroll
      for (int j = 0; j < 6; ++j) {
        if (vals[j] > v) { v = vals[j]; idx = lane + 64*j; }
      }
      #pragma unroll
      for (int o = 1; o < 64; o <<= 1) {
        float ov = __shfl_xor(v, o, 64);
        int oi = __shfl_xor(idx, o, 64);
        if (ov > v || (ov == v && oi < idx)) { v = ov; idx = oi; }
      }
      if (lane == 0) sel[it] = idx;
      ss += __expf(v - M);         // winner's exp, no LDS re-read
      #pragma unroll
      for (int j = 0; j < 6; ++j)
        if (lane + 64*j == idx) vals[j] = -1e30f;
    }
    if (lane == 0) sc[0] = ss*invS + 1e-8f;
  }
  __syncthreads();
  float dn = 1.0f/sc[0];
  for (int m = t; m < NNODES; m += 256) {
    float val = 0.0f;
    #pragma unroll
    for (int k = 0; k < 10; ++k) val = (m == sel[k]) ? pb[m]*invS*dn : val;
    outrow[m] = val;
  }
}

// --------------------------------------------------- k1: static adjacencies
__global__ void __launch_bounds__(256)
k1_static(const float* __restrict__ le1, const float* __restrict__ le2,
          const float* __restrict__ ge1, const float* __restrict__ ge2,
          const float* __restrict__ temp, float* __restrict__ outstat)
{
  __shared__ float e1[64], lg[NNODES], pb[NNODES], redv[4], sc[1];
  __shared__ int sel[10];
  int blk = blockIdx.x, t = threadIdx.x;
  int h = blk / NNODES, n = blk - h*NNODES;
  int kd; const float *e1p, *e2p; float tau;
  if (h < 2) {
    kd = 32;
    e1p = le1 + ((size_t)h*NNODES + n)*32;
    e2p = le2 + (size_t)h*32*NNODES;
    tau = fminf(fmaxf(temp[h]*2.0f, 0.1f), 5.0f);
  } else {
    kd = 64;
    e1p = ge1 + ((size_t)(h-2)*NNODES + n)*64;
    e2p = ge2 + (size_t)(h-2)*64*NNODES;
    tau = fminf(fmaxf(temp[h]*0.5f, 0.1f), 2.0f);
  }
  if (t < kd) e1[t] = e1p[t];
  __syncthreads();
  for (int m = t; m < NNODES; m += 256) {
    float s = 0.0f;
    for (int k = 0; k < kd; ++k) s += e1[k]*e2p[k*NNODES + m];
    lg[m] = fmaxf(s, 0.0f)/tau;
  }
  __syncthreads();
  softmax_topk_row(lg, pb, redv, sc, sel, outstat + (size_t)blk*NNODES);
}

// --------------------------------------- k2a: per-(seq,head) attention
// LDS 12960 floats = 51,840 B -> 3 blocks/CU
#define A_XS  0        // 72x100 x tile; S (72x76) aliases after QKV
#define A_QH  7200
#define A_KT  9216
#define A_VT  11040
#define A_TOT 12960

__global__ void __launch_bounds__(256)
k2a_attn(const float* __restrict__ pf, const float* __restrict__ pos,
         const float* __restrict__ inb, float* __restrict__ ws,
         int s0, int aoAbs)
{
  __shared__ float L[A_TOT];
  int blk = blockIdx.x, t = threadIdx.x;
  int h = blk & 3;
  int local = blk >> 2;
  size_t s = (size_t)s0 + local;
  int aoIdx = aoAbs ? (int)s : local;
  const float* prp = pf + s*(PP*DIM);
  for (int idx = t; idx < PP*DIM; idx += 256) {
    int p = idx/DIM, e = idx - p*DIM;
    L[A_XS + p*100 + e] = prp[idx];
  }
  __syncthreads();
  if (h == 0 && t < DIM) {            // pf.mean over P (pre pos-enc)
    float sm = 0.0f;
    for (int p = 0; p < PP; ++p) sm += L[A_XS + p*100 + t];
    ws[WS_PRM + s*DIM + t] = sm*(1.0f/72.0f);
  }
  __syncthreads();
  for (int idx = t; idx < PP*DIM; idx += 256) {
    int p = idx/DIM, e = idx - p*DIM;
    L[A_XS + p*100 + e] += pos[idx];
  }
  __syncthreads();
  const float* Wt2 = ws + WS_WT2 + (size_t)h*96*72;
  const float SC = 0.20412414523193150f;  // 1/sqrt(24)
  if (t < 216) {                      // QKV: 18 p-tiles(4) x 12 col-tiles(6)
    int pt = t / 12, jt = t - pt*12;
    int p0 = pt*4, gc0 = jt*6;
    float acc[4][6];
    #pragma unroll
    for (int a = 0; a < 4; ++a)
      #pragma unroll
      for (int c = 0; c < 6; ++c) acc[a][c] = 0.0f;
    for (int k0 = 0; k0 < 96; k0 += 4) {
      float4 xv[4];
      #pragma unroll
      for (int a = 0; a < 4; ++a) xv[a] = *(const float4*)&L[A_XS + (p0+a)*100 + k0];
      const float* wr = Wt2 + (size_t)k0*72 + gc0;
      #pragma unroll
      for (int kk = 0; kk < 4; ++kk) {
        float2 w01 = *(const float2*)(wr + kk*72);
        float2 w23 = *(const float2*)(wr + kk*72 + 2);
        float2 w45 = *(const float2*)(wr + kk*72 + 4);
        float wv[6] = {w01.x, w01.y, w23.x, w23.y, w45.x, w45.y};
        #pragma unroll
        for (int a = 0; a < 4; ++a) {
          float xa = ((const float*)&xv[a])[kk];
          #pragma unroll
          for (int c = 0; c < 6; ++c) acc[a][c] += xa*wv[c];
        }
      }
    }
    int g = jt >> 2;          // 0=q,1=k,2=v
    int c0 = (jt & 3)*6;
    #pragma unroll
    for (int c = 0; c < 6; ++c) {
      int cc = c0 + c;
      float bias = inb[g*96 + h*24 + cc];
      #pragma unroll
      for (int a = 0; a < 4; ++a) {
        float v = acc[a][c] + bias;
        int p = p0 + a;
        if (g == 0)      L[A_QH + p*28 + cc] = v*SC;
        else if (g == 1) L[A_KT + cc*76 + p] = v;
        else             L[A_VT + cc*76 + p] = v;
      }
    }
  }
  __syncthreads();
  for (int tile = t; tile < 648; tile += 256) {  // S = q k^T
    int pt = tile / 18, jt = tile - pt*18;
    int p0 = pt*2, j0 = jt*4;
    float a0=0,a1=0,a2=0,a3=0, c0=0,c1=0,c2=0,c3=0;
    #pragma unroll
    for (int d0 = 0; d0 < 24; d0 += 4) {
      float4 q0 = *(const float4*)&L[A_QH + p0*28 + d0];
      float4 q1 = *(const float4*)&L[A_QH + (p0+1)*28 + d0];
      #pragma unroll
      for (int dd = 0; dd < 4; ++dd) {
        float4 kv = *(const float4*)&L[A_KT + (d0+dd)*76 + j0];
        float qa = ((const float*)&q0)[dd];
        float qb = ((const float*)&q1)[dd];
        a0 += qa*kv.x; a1 += qa*kv.y; a2 += qa*kv.z; a3 += qa*kv.w;
        c0 += qb*kv.x; c1 += qb*kv.y; c2 += qb*kv.z; c3 += qb*kv.w;
      }
    }
    *(float4*)&L[A_XS + p0*76 + j0]     = make_float4(a0,a1,a2,a3);
    *(float4*)&L[A_XS + (p0+1)*76 + j0] = make_float4(c0,c1,c2,c3);
  }
  __syncthreads();
  if (t < 72) {                       // row softmax
    float* row = &L[A_XS + t*76];
    float mx = row[0];
    for (int j = 1; j < 72; ++j) mx = fmaxf(mx, row[j]);
    float sm = 0.0f;
    for (int j = 0; j < 72; ++j) { float e = __expf(row[j]-mx); row[j] = e; sm += e; }
    float inv = 1.0f/sm;
    for (int j = 0; j < 72; ++j) row[j] *= inv;
  }
  __syncthreads();
  if (t < 216) {                      // O = P @ V -> ao (f32)
    int pt = t / 6, dt = t - pt*6;
    int p0 = pt*2, d0 = dt*4;
    float acc[2][4];
    #pragma unroll
    for (int a = 0; a < 2; ++a)
      #pragma unroll
      for (int dd = 0; dd < 4; ++dd) acc[a][dd] = 0.0f;
    for (int j0 = 0; j0 < 72; j0 += 4) {
      float4 pv0 = *(const float4*)&L[A_XS + p0*76 + j0];
      float4 pv1 = *(const float4*)&L[A_XS + (p0+1)*76 + j0];
      #pragma unroll
      for (int dd = 0; dd < 4; ++dd) {
        float4 vv = *(const float4*)&L[A_VT + (d0+dd)*76 + j0];
        acc[0][dd] += pv0.x*vv.x + pv0.y*vv.y + pv0.z*vv.z + pv0.w*vv.w;
        acc[1][dd] += pv1.x*vv.x + pv1.y*vv.y + pv1.z*vv.z + pv1.w*vv.w;
      }
    }
    float* aob = ws + WS_AO + (size_t)aoIdx*PP*DIM;
    #pragma unroll
    for (int a = 0; a < 2; ++a)
      #pragma unroll
      for (int dd = 0; dd < 4; ++dd)
        aob[(p0+a)*DIM + h*24 + d0 + dd] = acc[a][dd];
  }
}

// -------------------- k2b: node epilogue + dynamic encoder
#define B_AO   0      // 72 x 97
#define B_LIMP 6984
#define B_IMP  7056
#define B_WSUM 7128
#define B_NB   7224
#define B_NR   7320
#define B_WB   7416
#define B_H1   7512
#define B_G1   7640
#define B_H2   7768
#define B_TOT  7832

__global__ void __launch_bounds__(128)
k2b_node(float* __restrict__ ws,
         const float* __restrict__ wo, const float* __restrict__ bo,
         const float* __restrict__ tng, const float* __restrict__ tnb,
         const float* __restrict__ dw1, const float* __restrict__ db1,
         const float* __restrict__ dg1, const float* __restrict__ dlb1,
         const float* __restrict__ dw2, const float* __restrict__ db2,
         const float* __restrict__ dg2, const float* __restrict__ dlb2,
         int s0, int aoAbs)
{
  __shared__ float L[B_TOT];
  int blk = blockIdx.x, t = threadIdx.x;
  size_t s = (size_t)s0 + blk;
  int aoIdx = aoAbs ? (int)s : blk;
  const float* aob = ws + WS_AO + (size_t)aoIdx*PP*DIM;
  for (int idx = t; idx < PP*DIM; idx += 128) {
    int p = idx/DIM, e = idx - p*DIM;
    L[B_AO + p*97 + e] = aob[idx];
  }
  if (t < 96) L[B_WB + t] = ws[WS_WBAR + t];
  __syncthreads();
  if (t < 72) {    // att.mean(-1) == ao . wbar + bbar
    float sm = 0.0f;
    for (int e = 0; e < 96; ++e) sm += L[B_AO + t*97 + e]*L[B_WB + e];
    L[B_LIMP + t] = sm + ws[WS_BBAR];
  }
  __syncthreads();
  if (t < 72) {
    float mx = L[B_LIMP];
    for (int j = 1; j < 72; ++j) mx = fmaxf(mx, L[B_LIMP+j]);
    float sm = 0.0f;
    for (int j = 0; j < 72; ++j) sm += __expf(L[B_LIMP+j]-mx);
    L[B_IMP + t] = __expf(L[B_LIMP+t]-mx)/sm;
  }
  __syncthreads();
  if (t < 96) {
    float sm = 0.0f;
    for (int p = 0; p < PP; ++p) sm += L[B_IMP+p]*L[B_AO + p*97 + t];
    L[B_WSUM + t] = sm;
  }
  __syncthreads();
  if (t < 96) {
    float sm = 0.0f;
    for (int e = 0; e < 96; ++e) sm += L[B_WSUM+e]*wo[t*96 + e];
    L[B_NB + t] = sm + bo[t] + ws[WS_PRM + s*DIM + t];
  }
  __syncthreads();
  if (t < 96) {
    float mean = 0.0f;
    for (int e = 0; e < 96; ++e) mean += L[B_NB+e];
    mean *= (1.0f/96.0f);
    float var = 0.0f;
    for (int e = 0; e < 96; ++e) { float d = L[B_NB+e]-mean; var += d*d; }
    var *= (1.0f/96.0f);
    L[B_NR + t] = (L[B_NB+t]-mean)*rsqrtf(var+1e-5f)*tng[t] + tnb[t];
  }
  __syncthreads();
  {
    float sm = 0.0f;
    for (int k = 0; k < 96; ++k) sm += L[B_NR+k]*dw1[t*96 + k];
    L[B_H1 + t] = sm + db1[t];
  }
  __syncthreads();
  {
    float mean = 0.0f; for (int e = 0; e < 128; ++e) mean += L[B_H1+e];
    mean *= (1.0f/128.0f);
    float var = 0.0f; for (int e = 0; e < 128; ++e) { float d = L[B_H1+e]-mean; var += d*d; }
    var *= (1.0f/128.0f);
    float y = (L[B_H1+t]-mean)*rsqrtf(var+1e-5f)*dg1[t] + dlb1[t];
    L[B_G1 + t] = gelu_f(y);
  }
  __syncthreads();
  if (t < 64) {
    float sm = 0.0f;
    for (int k = 0; k < 128; ++k) sm += L[B_G1+k]*dw2[t*128 + k];
    L[B_H2 + t] = sm + db2[t];
  }
  __syncthreads();
  if (t < 64) {
    float mean = 0.0f; for (int e = 0; e < 64; ++e) mean += L[B_H2+e];
    mean *= (1.0f/64.0f);
    float var = 0.0f; for (int e = 0; e < 64; ++e) { float d = L[B_H2+e]-mean; var += d*d; }
    var *= (1.0f/64.0f);
    ws[WS_DEA + s*ND + t] = (L[B_H2+t]-mean)*rsqrtf(var+1e-5f)*dg2[t] + dlb2[t];
  }
}

// ------------------------------------------------ k4t: transpose de for GNN
__global__ void k4t_transpose(float* __restrict__ ws, int deoff)
{
  int bd = blockIdx.x;
  int b = bd >> 6, d = bd & 63;
  for (int m = threadIdx.x; m < NNODES; m += 256)
    ws[WS_DETG + (size_t)bd*360 + m] = ws[deoff + ((size_t)b*NNODES + m)*ND + d];
}

// --------------------------------------------------------- k4: one GNN layer
__global__ void __launch_bounds__(256)
k4_gnn(float* __restrict__ ws, int inoff, int outoff,
       const float* __restrict__ w, const float* __restrict__ bb,
       const float* __restrict__ g, const float* __restrict__ beta)
{
  __shared__ float nrow[64], lg[NNODES], pb[NNODES], aggp[4][64], aggb[64], prj[64], redv[4];
  int blk = blockIdx.x, t = threadIdx.x;
  int b = blk / NNODES;
  if (t < 64) nrow[t] = ws[inoff + (size_t)blk*ND + t];
  __syncthreads();
  const float* dg = ws + WS_DETG + (size_t)b*64*360;
  for (int m = t; m < NNODES; m += 256) {
    float sm = 0.0f;
    for (int d = 0; d < 64; ++d) sm += nrow[d]*dg[d*360 + m];
    lg[m] = sm/0.2f;
  }
  __syncthreads();
  int lane = t & 63, wv = t >> 6;
  float mx = -1e30f;
  for (int m = t; m < NNODES; m += 256) mx = fmaxf(mx, lg[m]);
  for (int o = 32; o; o >>= 1) mx = fmaxf(mx, __shfl_down(mx, o, 64));
  if (lane == 0) redv[wv] = mx;
  __syncthreads();
  float M = fmaxf(fmaxf(redv[0],redv[1]),fmaxf(redv[2],redv[3]));
  float ls = 0.0f;
  for (int m = t; m < NNODES; m += 256) { float e = __expf(lg[m]-M); pb[m] = e; ls += e; }
  for (int o = 32; o; o >>= 1) ls += __shfl_down(ls, o, 64);
  __syncthreads();
  if (lane == 0) redv[wv] = ls;
  __syncthreads();
  float inv = 1.0f/(redv[0]+redv[1]+redv[2]+redv[3]);
  for (int m = t; m < NNODES; m += 256) pb[m] *= inv;
  __syncthreads();
  {  // agg = sims @ de : 4-wave split over m, coalesced de reads
    int d = lane, q = wv;
    float sm = 0.0f;
    for (int m = q; m < NNODES; m += 4)
      sm += pb[m]*ws[inoff + ((size_t)(b*NNODES + m))*ND + d];
    aggp[q][d] = sm;
  }
  __syncthreads();
  if (t < 64) aggb[t] = aggp[0][t]+aggp[1][t]+aggp[2][t]+aggp[3][t];
  __syncthreads();
  if (t < 64) {
    float sm = 0.0f;
    for (int d = 0; d < 64; ++d) sm += aggb[d]*w[t*64 + d];
    prj[t] = sm + bb[t];
  }
  __syncthreads();
  if (t < 64) {
    float mean = 0.0f; for (int e = 0; e < 64; ++e) mean += prj[e];
    mean *= (1.0f/64.0f);
    float var = 0.0f; for (int e = 0; e < 64; ++e) { float d = prj[e]-mean; var += d*d; }
    var *= (1.0f/64.0f);
    float y = (prj[t]-mean)*rsqrtf(var+1e-5f)*g[t] + beta[t];
    ws[outoff + (size_t)blk*ND + t] = gelu_f(y) + nrow[t];
  }
}

// ----------------------------------------------- k5: dynamic adj + top-k
__global__ void __launch_bounds__(256)
k5_dyn(const float* __restrict__ ws, const float* __restrict__ se2,
       const float* __restrict__ temp, float* __restrict__ outdyn)
{
  __shared__ float den[64], lg[NNODES], pb[NNODES], redv[4], sc[1];
  __shared__ int sel[10];
  int blk = blockIdx.x, t = threadIdx.x;
  int n = blk % NNODES;
  int bh = blk / NNODES;
  int h = bh & 3, b = bh >> 2;
  if (t < 64) den[t] = ws[WS_DEA + ((size_t)b*NNODES + n)*ND + t];
  __syncthreads();
  float tau = fminf(fmaxf(temp[h], 0.1f), 2.0f);
  const float* sp = se2 + (size_t)h*64*NNODES;
  for (int m = t; m < NNODES; m += 256) {
    float sm = 0.0f;
    for (int d = 0; d < 64; ++d) sm += den[d]*sp[d*NNODES + m];
    lg[m] = fmaxf(sm, 0.0f)/tau;
  }
  __syncthreads();
  softmax_topk_row(lg, pb, redv, sc, sel, outdyn + (size_t)blk*NNODES);
}

// ---------------------------------- k6: fusion + edge encoder + final adj
__global__ void __launch_bounds__(256)
k6_fuse(const float* __restrict__ ws, const float* __restrict__ outstat,
        const float* __restrict__ outdyn,
        const float* __restrict__ gfw, const float* __restrict__ gfb,
        const float* __restrict__ ew1, const float* __restrict__ eb1,
        const float* __restrict__ elg, const float* __restrict__ elb,
        const float* __restrict__ ew2, const float* __restrict__ eb2,
        const float* __restrict__ ew3, const float* __restrict__ eb3,
        float* __restrict__ outfin)
{
  __shared__ float sw1[64], sb1[16], slg[16], slb[16], sw2[128], sb2[8], sw3[8], sb3[1], sfw[4];
  int blk = blockIdx.x, t = threadIdx.x;
  int b = blk / NNODES, n = blk - b*NNODES;
  if (t < 64)  sw1[t] = ew1[t];
  if (t < 16)  { sb1[t] = eb1[t]; slg[t] = elg[t]; slb[t] = elb[t]; }
  if (t < 128) sw2[t] = ew2[t];
  if (t < 8)   { sb2[t] = eb2[t]; sw3[t] = ew3[t]; }
  if (t == 0)  sb3[0] = eb3[0];
  if (t < 4) {
    const float* pm = ws + WS_PRM + (size_t)blk*DIM;
    float sm = gfb[t];
    for (int e = 0; e < DIM; ++e) sm += pm[e]*gfw[t*DIM + e];
    sfw[t] = 1.0f/(1.0f+__expf(-sm));
  }
  __syncthreads();
  size_t srow = (size_t)n*NNODES;
  for (int m = t; m < NNODES; m += 256) {
    float fu[4]; float mn = 0.0f;
    #pragma unroll
    for (int hh = 0; hh < 4; ++hh) {
      float sv = outstat[(size_t)hh*NN2 + srow + m];
      float dv = outdyn[((size_t)(b*4+hh)*NNODES + n)*NNODES + m];
      float f = (1.0f - sfw[hh])*sv + sfw[hh]*dv;
      fu[hh] = f; mn += f;
    }
    mn *= 0.25f;
    float h1[16]; float m1 = 0.0f;
    #pragma unroll
    for (int j = 0; j < 16; ++j) {
      float sm = sb1[j];
      #pragma unroll
      for (int c = 0; c < 4; ++c) sm += fu[c]*sw1[j*4+c];
      h1[j] = sm; m1 += sm;
    }
    m1 *= (1.0f/16.0f);
    float v1 = 0.0f;
    #pragma unroll
    for (int j = 0; j < 16; ++j) { float d = h1[j]-m1; v1 += d*d; }
    float is1 = rsqrtf(v1*(1.0f/16.0f) + 1e-5f);
    #pragma unroll
    for (int j = 0; j < 16; ++j) h1[j] = gelu_f((h1[j]-m1)*is1*slg[j] + slb[j]);
    float h2[8];
    #pragma unroll
    for (int i = 0; i < 8; ++i) {
      float sm = sb2[i];
      #pragma unroll
      for (int j = 0; j < 16; ++j) sm += h1[j]*sw2[i*16+j];
      h2[i] = gelu_f(sm);
    }
    float ewv = sb3[0];
    #pragma unroll
    for (int i = 0; i < 8; ++i) ewv += h2[i]*sw3[i];
    float fin = (1.0f/(1.0f+__expf(-ewv)))*mn;
    outfin[(size_t)b*NN2 + srow + m] = fin;
  }
}

// ------------------------------------------------------------- launch
extern "C" void kernel_launch(void* const* d_in, const int* in_sizes, int n_in,
                              void* d_out, int out_size, void* d_ws, size_t ws_size,
                              hipStream_t stream)
{
  const float* pf   = (const float*)d_in[0];
  const float* se2  = (const float*)d_in[1];
  const float* le1  = (const float*)d_in[2];
  const float* le2  = (const float*)d_in[3];
  const float* ge1  = (const float*)d_in[4];
  const float* ge2  = (const float*)d_in[5];
  const float* temp = (const float*)d_in[6];
  const float* wi   = (const float*)d_in[7];
  const float* inb  = (const float*)d_in[8];
  const float* wo   = (const float*)d_in[9];
  const float* bo   = (const float*)d_in[10];
  const float* tng  = (const float*)d_in[11];
  const float* tnb  = (const float*)d_in[12];
  const float* dw1  = (const float*)d_in[13];
  const float* db1  = (const float*)d_in[14];
  const float* dg1  = (const float*)d_in[15];
  const float* dlb1 = (const float*)d_in[16];
  const float* dw2  = (const float*)d_in[17];
  const float* db2  = (const float*)d_in[18];
  const float* dg2  = (const float*)d_in[19];
  const float* dlb2 = (const float*)d_in[20];
  const float* pos  = (const float*)d_in[21];
  const float* g1w  = (const float*)d_in[22];
  const float* g1b  = (const float*)d_in[23];
  const float* g1g  = (const float*)d_in[24];
  const float* g1be = (const float*)d_in[25];
  const float* g2w  = (const float*)d_in[26];
  const float* g2b  = (const float*)d_in[27];
  const float* g2g  = (const float*)d_in[28];
  const float* g2be = (const float*)d_in[29];
  const float* gfw  = (const float*)d_in[30];
  const float* gfb  = (const float*)d_in[31];
  const float* ew1  = (const float*)d_in[32];
  const float* eb1  = (const float*)d_in[33];
  const float* elg  = (const float*)d_in[34];
  const float* elb  = (const float*)d_in[35];
  const float* ew2  = (const float*)d_in[36];
  const float* eb2  = (const float*)d_in[37];
  const float* ew3  = (const float*)d_in[38];
  const float* eb3  = (const float*)d_in[39];
  float* ws = (float*)d_ws;
  float* out = (float*)d_out;
  float* outfin  = out;                            // (B,N,N)
  float* outstat = out + (size_t)NB*NN2;           // (H,N,N)
  float* outdyn  = out + (size_t)(NB+NH)*NN2;      // (B,H,N,N)

  k0_setup<<<1, 256, 0, stream>>>(wi, wo, bo, ws);
  k1_static<<<NH*NNODES, 256, 0, stream>>>(le1, le2, ge1, ge2, temp, outstat);

  // full-batch ao if workspace allows (deterministic in ws_size -> graph-safe)
  size_t needFull = ((size_t)WS_AO + (size_t)SEQ*PP*DIM) * sizeof(float);
  if (ws_size >= needFull) {
    k2a_attn<<<SEQ*NH, 256, 0, stream>>>(pf, pos, inb, ws, 0, 1);
    k2b_node<<<SEQ, 128, 0, stream>>>(ws, wo, bo, tng, tnb,
                                      dw1, db1, dg1, dlb1, dw2, db2, dg2, dlb2, 0, 1);
  } else {
    for (int B0 = 0; B0 < NB; ++B0) {
      k2a_attn<<<NNODES*NH, 256, 0, stream>>>(pf, pos, inb, ws, B0*NNODES, 0);
      k2b_node<<<NNODES, 128, 0, stream>>>(ws, wo, bo, tng, tnb,
                                           dw1, db1, dg1, dlb1, dw2, db2, dg2, dlb2,
                                           B0*NNODES, 0);
    }
  }
  k4t_transpose<<<512, 256, 0, stream>>>(ws, WS_DEA);
  k4_gnn<<<SEQ, 256, 0, stream>>>(ws, WS_DEA, WS_DEB, g1w, g1b, g1g, g1be);
  k4t_transpose<<<512, 256, 0, stream>>>(ws, WS_DEB);
  k4_gnn<<<SEQ, 256, 0, stream>>>(ws, WS_DEB, WS_DEA, g2w, g2b, g2g, g2be);
  k5_dyn<<<NB*NH*NNODES, 256, 0, stream>>>(ws, se2, temp, outdyn);
  k6_fuse<<<SEQ, 256, 0, stream>>>(ws, outstat, outdyn, gfw, gfb,
                                   ew1, eb1, elg, elb, ew2, eb2, ew3, eb3, outfin);
}